// Round 3
// baseline (225.511 us; speedup 1.0000x reference)
//
#include <hip/hip_runtime.h>
#include <hip/hip_bf16.h>
#include <math.h>

// CrossGeometricStructureEmbedding, round 3: occupancy-focused.
// R2 post-mortem: 78 us steady at 17% occupancy — latency-bound, not pipe-bound
// (128 VGPR bw[] + 64 AGPR acc => 2 waves/SIMD; 69 KB LDS => 2 blocks/CU).
// R3: stream B-fragments from global (W is L2-resident, ~1 GB total L2 reads
// ~30 us on a pipe nothing else uses), single-buffer E (34 KB), cap regs via
// __launch_bounds__(256,3) => target 3 blocks/CU, ~37% occupancy.
// Grid = 2 types x (4096/8) point-groups = 1024 blocks.

typedef __attribute__((ext_vector_type(8))) short short8;
typedef __attribute__((ext_vector_type(4))) float f32x4;
typedef __attribute__((ext_vector_type(4))) unsigned int uint4v;

#define HH 256
#define P_PTS 8
#define NPTS 4096

__device__ __forceinline__ unsigned short f2bf(float f) {
    union { float f; unsigned int u; } v; v.f = f;
    unsigned int r = v.u + 0x7fffu + ((v.u >> 16) & 1u);  // RNE
    return (unsigned short)(r >> 16);
}

__device__ __forceinline__ unsigned int pack_sc(float s, float c) {
    union { __hip_bfloat162 h; unsigned int u; } v;
    v.h = __float22bfloat162_rn(make_float2(s, c));  // low = sin, high = cos
    return v.u;
}

__global__ __launch_bounds__(256)
void prep_w_kernel(const float* __restrict__ Wa, const float* __restrict__ Wd,
                   unsigned short* __restrict__ wbf) {
    int i = blockIdx.x * 256 + threadIdx.x;
    if (i < HH * HH) {
        wbf[i] = f2bf(Wd[i]);             // [0, 65536): Wd bf16
        wbf[HH * HH + i] = f2bf(Wa[i]);   // [65536, 131072): Wa bf16
    }
}

__global__ __launch_bounds__(256, 3)
void cgse_main(const float* __restrict__ points,
               const float* __restrict__ anchors,
               const unsigned short* __restrict__ wbf,
               const float* __restrict__ ba,
               const float* __restrict__ bd,
               float* __restrict__ out) {
    __shared__ __align__(16) unsigned short E[64][264];  // 33.8 KB, single buffer
    __shared__ float xs[2][64];
    __shared__ float anch[192];

    const int tid = threadIdx.x;
    const int wave = tid >> 6, lane = tid & 63;
    const int quad = lane >> 4, l16 = lane & 15;
    const int type = blockIdx.x & 1;            // 0 = d (Wd), 1 = a (Wa)
    const int base = (blockIdx.x >> 1) * P_PTS;

    const unsigned short* W = wbf + type * (HH * HH);
    // B-fragment base: this lane's slice of W for its wave's 64-col strip.
    const unsigned short* wb = W + (wave * 64 + l16) * HH + quad * 8;

    // biases: only the d-type blocks add (ba + bd); a-type adds raw max
    float bias[4];
    #pragma unroll
    for (int nt = 0; nt < 4; ++nt) {
        const int c = wave * 64 + nt * 16 + l16;
        bias[nt] = (type == 0) ? (ba[c] + bd[c]) : 0.0f;
    }

    // div_term split: pair index i = ks*16 + quad*4 + j
    // dt0[j] = 10000^(-(quad*4+j)/128); rk[ks] = 10000^(-ks/8)
    float dt0[4];
    #pragma unroll
    for (int j = 0; j < 4; ++j)
        dt0[j] = __expf(-(float)(quad * 4 + j) * 0.0719557841560639f);
    const float rk[8] = {1.0f, 0.31622776601683794f, 0.1f, 0.031622776601683794f,
                         0.01f, 0.0031622776601683794f, 0.001f, 0.00031622776601683794f};

    auto geom = [&](int pn, int slot) {
        if (tid < 64) {
            const float px = points[pn * 3 + 0], py = points[pn * 3 + 1], pz = points[pn * 3 + 2];
            const int k = tid;
            const float r1x = px - anch[k * 3 + 0];
            const float r1y = py - anch[k * 3 + 1];
            const float r1z = pz - anch[k * 3 + 2];
            float v;
            if (type == 0) {
                v = sqrtf(r1x * r1x + r1y * r1y + r1z * r1z) * 5.0f;  // /SIGMA_D
            } else {
                const int k2 = (k + 1) & 63;  // roll(-1)
                const float r2x = px - anch[k2 * 3 + 0];
                const float r2y = py - anch[k2 * 3 + 1];
                const float r2z = pz - anch[k2 * 3 + 2];
                const float cx = r1y * r2z - r1z * r2y;
                const float cy = r1z * r2x - r1x * r2z;
                const float cz = r1x * r2y - r1y * r2x;
                const float sv = sqrtf(cx * cx + cy * cy + cz * cz);
                const float cv = r1x * r2x + r1y * r2y + r1z * r2z;
                v = atan2f(sv, cv) * 3.8197186342054885f;  // *180/(15*pi)
            }
            xs[slot][k] = v;
        }
    };

    const int frow = wave * 16 + l16;  // row this thread fills

    if (tid < 192) anch[tid] = anchors[tid];
    __syncthreads();
    geom(base + 0, 0);
    __syncthreads();  // xs[0] ready

    for (int q = 0; q < P_PTS; ++q) {
        const int b = q & 1;

        // prefetch B for ks=0 (global/L2; independent of LDS fill & barrier)
        short8 bfr[4];
        #pragma unroll
        for (int nt = 0; nt < 4; ++nt)
            bfr[nt] = *(const short8*)(wb + nt * 16 * HH);

        // ---- fill E with point q's embedding (single buffer)
        {
            const float xv = xs[b][frow];
            float xq[4];
            #pragma unroll
            for (int j = 0; j < 4; ++j) xq[j] = xv * dt0[j];
            #pragma unroll
            for (int ks = 0; ks < 8; ++ks) {
                uint4v w;
                #pragma unroll
                for (int j = 0; j < 4; ++j) {
                    float s, c;
                    __sincosf(xq[j] * rk[ks], &s, &c);
                    w[j] = pack_sc(s, c);
                }
                *(uint4v*)&E[frow][ks * 32 + quad * 8] = w;
            }
        }
        __syncthreads();  // E ready

        if (q + 1 < P_PTS) geom(base + q + 1, b ^ 1);  // overlaps MFMA below

        f32x4 acc[4][4];
        #pragma unroll
        for (int mt = 0; mt < 4; ++mt)
            #pragma unroll
            for (int nt = 0; nt < 4; ++nt)
                acc[mt][nt] = (f32x4){0.f, 0.f, 0.f, 0.f};

        #pragma unroll
        for (int ks = 0; ks < 8; ++ks) {
            short8 bnext[4];
            if (ks < 7) {
                #pragma unroll
                for (int nt = 0; nt < 4; ++nt)
                    bnext[nt] = *(const short8*)(wb + nt * 16 * HH + (ks + 1) * 32);
            }
            short8 afr[4];
            #pragma unroll
            for (int mt = 0; mt < 4; ++mt)
                afr[mt] = *(const short8*)&E[mt * 16 + l16][ks * 32 + quad * 8];
            #pragma unroll
            for (int nt = 0; nt < 4; ++nt)
                #pragma unroll
                for (int mt = 0; mt < 4; ++mt)
                    acc[mt][nt] = __builtin_amdgcn_mfma_f32_16x16x32_bf16(
                        afr[mt], bfr[nt], acc[mt][nt], 0, 0, 0);
            #pragma unroll
            for (int nt = 0; nt < 4; ++nt) bfr[nt] = bnext[nt];
        }

        #pragma unroll
        for (int nt = 0; nt < 4; ++nt) {
            float m = fmaxf(fmaxf(acc[0][nt][0], acc[0][nt][1]),
                            fmaxf(acc[0][nt][2], acc[0][nt][3]));
            #pragma unroll
            for (int mt = 1; mt < 4; ++mt)
                m = fmaxf(m, fmaxf(fmaxf(acc[mt][nt][0], acc[mt][nt][1]),
                                   fmaxf(acc[mt][nt][2], acc[mt][nt][3])));
            m = fmaxf(m, __shfl_down(m, 32));
            m = fmaxf(m, __shfl_down(m, 16));  // lanes 0..15: max over 64 anchors
            if (lane < 16)
                unsafeAtomicAdd(&out[(base + q) * HH + wave * 64 + nt * 16 + l16],
                                m + bias[nt]);
        }
        __syncthreads();  // E consumed; safe to refill next q
    }
}

extern "C" void kernel_launch(void* const* d_in, const int* in_sizes, int n_in,
                              void* d_out, int out_size, void* d_ws, size_t ws_size,
                              hipStream_t stream) {
    const float* points  = (const float*)d_in[0];
    const float* anchors = (const float*)d_in[1];
    // d_in[2] = cor_score: unused by the reference
    const float* Wa = (const float*)d_in[3];
    const float* ba = (const float*)d_in[4];
    const float* Wd = (const float*)d_in[5];
    const float* bd = (const float*)d_in[6];

    unsigned short* wbf = (unsigned short*)d_ws;  // 256 KB: Wd|Wa bf16

    hipMemsetAsync(d_out, 0, (size_t)NPTS * HH * sizeof(float), stream);
    hipLaunchKernelGGL(prep_w_kernel, dim3(256), dim3(256), 0, stream, Wa, Wd, wbf);
    hipLaunchKernelGGL(cgse_main, dim3(2 * (NPTS / P_PTS)), dim3(256), 0, stream,
                       points, anchors, wbf, ba, bd, (float*)d_out);
}